// Round 13
// baseline (47.848 us; speedup 1.0000x reference)
//
#include <hip/hip_runtime.h>
#include <stdint.h>

// FlagBagEncoder: out[t,:] = mean over {k : flags[t,k] > 0.5} of W[k,:], zeros if empty.
// T=100000, K=512, D=64, fp32 in/out.
//
// v13: v8 structure (stream-first, in-kernel W->sB convert overlapping streams,
// ONE barrier, phase M from LDS) with 32-ROW TILES VIA WAVE PAIRS to halve the
// post-barrier LDS tail (the ~7.5 us/CU of B-table reads that can't hide under
// the stream because all streams end together):
//   - pair of waves shares a 32-row tile; each wave streams 16 rows EXACTLY as
//     v8 (row-sequential, depth-4 ring) and writes its private 1-KB sM half.
//   - phase M n-split: wave A -> cols 0-31 (nt 0,1), wave B -> cols 32-63
//     (nt 2,3). Each wave reads 2 A-fragments/step (both row-groups, from the
//     pair's two sM halves) x 2 B slices -> 4 independent MFMA chains (v8 ILP),
//     but only 32 KB of B-LDS reads per wave (v8: 64 KB).
// k-map (identical for A and B, permutation cancels): k = 128*kq + 8*s + e.

#define T_ROWS 100000
#define K_FLAGS 512
#define D_DIM 64
#define TILES32 (T_ROWS / 32)   // 3125, exact

typedef __attribute__((ext_vector_type(4))) float f32x4;
typedef __attribute__((ext_vector_type(8))) short bf16x8;

__device__ __forceinline__ uint32_t f32_to_bf16_rne(float f) {
  union { float f; uint32_t u; } v; v.f = f;
  uint32_t u = v.u;
  return (u + 0x7FFFu + ((u >> 16) & 1u)) >> 16;
}

__global__ __launch_bounds__(1024, 8) void flagbag_kernel(const float* __restrict__ flags,
                                                          const float* __restrict__ W,
                                                          float* __restrict__ out) {
  __shared__ uint4 sB[16 * 4 * 64];     // 64 KB B-fragment table: E = s*256 + nt*64 + lane
  __shared__ uint32_t sM[16][256];      // 1 KB per wave mask exchange (16 KB total)

  const int tid  = threadIdx.x;
  const int lane = tid & 63;
  const int wave = tid >> 6;
  const int pair = wave >> 1;
  const int mate = wave & 1;            // A=0: rows 0-15, cols 0-31 ; B=1: rows 16-31, cols 32-63
  const int slot = pair * 512 + (int)blockIdx.x;   // 8 pairs/block x 512 blocks = 4096 slots
  const bool active = (slot < TILES32);
  const int t0 = (active ? slot : 0) * 32;

  // ---- phase L FIRST: row-sequential contiguous stream of this wave's 16 rows ----
  if (active) {
    const float* ft = flags + (size_t)(t0 + 16 * mate) * K_FLAGS + lane * 8;

    uint32_t D0 = 0, D1 = 0, D2 = 0, D3 = 0;   // local rows 0-3 / 4-7 / 8-11 / 12-15
    f32x4 ra[4], rb[4];
#pragma unroll
    for (int r = 0; r < 3; ++r) {
      ra[r] = *reinterpret_cast<const f32x4*>(ft + r * K_FLAGS);
      rb[r] = *reinterpret_cast<const f32x4*>(ft + r * K_FLAGS + 4);
    }
#pragma unroll
    for (int r = 0; r < 16; ++r) {
      if (r + 3 < 16) {   // compile-time under full unroll
        ra[(r + 3) & 3] = *reinterpret_cast<const f32x4*>(ft + (r + 3) * K_FLAGS);
        rb[(r + 3) & 3] = *reinterpret_cast<const f32x4*>(ft + (r + 3) * K_FLAGS + 4);
      }
      const f32x4 a = ra[r & 3], b = rb[r & 3];
      uint32_t byte = 0;
#pragma unroll
      for (int j = 0; j < 4; ++j) {
        byte |= (a[j] > 0.5f) ? (1u << j)       : 0u;
        byte |= (b[j] > 0.5f) ? (1u << (j + 4)) : 0u;
      }
      const uint32_t sh = byte << ((r & 3) * 8);
      if ((r >> 2) == 0) D0 |= sh;
      else if ((r >> 2) == 1) D1 |= sh;
      else if ((r >> 2) == 2) D2 |= sh;
      else D3 |= sh;
    }

    uint32_t* sMw = sM[wave];
    sMw[0 * 64 + (lane ^ 0)]  = D0;
    sMw[1 * 64 + (lane ^ 4)]  = D1;
    sMw[2 * 64 + (lane ^ 8)]  = D2;
    sMw[3 * 64 + (lane ^ 12)] = D3;
  }

  // ---- W -> bf16 fragment table (overlaps other waves' streams) ----
#pragma unroll
  for (int p = 0; p < 4; ++p) {
    const int E  = tid + p * 1024;
    const int s  = E >> 8;
    const int nt = (E >> 6) & 3;
    const int ln = E & 63;
    const int n  = (ln & 15) + 16 * nt;
    const int kb = 128 * (ln >> 4) + 8 * s;
    uint32_t r[4];
#pragma unroll
    for (int j = 0; j < 4; ++j) {
      uint32_t lo = f32_to_bf16_rne(W[(size_t)(kb + 2 * j    ) * D_DIM + n]);
      uint32_t hi = f32_to_bf16_rne(W[(size_t)(kb + 2 * j + 1) * D_DIM + n]);
      r[j] = lo | (hi << 16);
    }
    sB[E] = make_uint4(r[0], r[1], r[2], r[3]);
  }
  __syncthreads();   // only barrier: orders sB AND both sM halves of each pair
  if (!active) return;

  // ---- phase M: n-split MFMA over the pair's 32 rows ----
  const int m  = lane & 15;   // A row within row-group / output col within n-tile
  const int kq = lane >> 4;
  const int mj = m >> 2, mb = m & 3;
  const int m4 = 4 * mj;
  const int C  = 4 * (mj * 64 + 16 * kq) + mb;
  const uint8_t* sA0 = reinterpret_cast<const uint8_t*>(sM[pair * 2    ]);  // rows 0-15
  const uint8_t* sA1 = reinterpret_cast<const uint8_t*>(sM[pair * 2 + 1]);  // rows 16-31
  const int ntb = 2 * mate;   // my two n-tiles: ntb, ntb+1

  f32x4 a00 = {0.f,0.f,0.f,0.f}, a01 = {0.f,0.f,0.f,0.f};
  f32x4 a10 = {0.f,0.f,0.f,0.f}, a11 = {0.f,0.f,0.f,0.f};
  int cntA = 0, cntB = 0;

  uint4 bc0 = sB[ntb * 64 + lane];
  uint4 bc1 = sB[(ntb + 1) * 64 + lane];

#pragma unroll
  for (int s = 0; s < 16; ++s) {
    uint4 bn0, bn1;
    if (s + 1 < 16) {   // compile-time under full unroll
      bn0 = sB[(s + 1) * 256 + ntb * 64 + lane];
      bn1 = sB[(s + 1) * 256 + (ntb + 1) * 64 + lane];
    }

    const uint32_t byteA = sA0[C + 4 * (s ^ m4)];   // row m,    k = 128kq+8s+e
    const uint32_t byteB = sA1[C + 4 * (s ^ m4)];   // row m+16, same k
    cntA += __popc(byteA);
    cntB += __popc(byteB);

    bf16x8 afA, afB;
#pragma unroll
    for (int e = 0; e < 8; ++e) {
      afA[e] = ((byteA >> e) & 1u) ? (short)0x3F80 : (short)0;
      afB[e] = ((byteB >> e) & 1u) ? (short)0x3F80 : (short)0;
    }

    a00 = __builtin_amdgcn_mfma_f32_16x16x32_bf16(afA, *reinterpret_cast<const bf16x8*>(&bc0), a00, 0, 0, 0);
    a01 = __builtin_amdgcn_mfma_f32_16x16x32_bf16(afA, *reinterpret_cast<const bf16x8*>(&bc1), a01, 0, 0, 0);
    a10 = __builtin_amdgcn_mfma_f32_16x16x32_bf16(afB, *reinterpret_cast<const bf16x8*>(&bc0), a10, 0, 0, 0);
    a11 = __builtin_amdgcn_mfma_f32_16x16x32_bf16(afB, *reinterpret_cast<const bf16x8*>(&bc1), a11, 0, 0, 0);

    bc0 = bn0; bc1 = bn1;
  }

  // full row counts: lanes {m, m+16, m+32, m+48} hold disjoint k-quarters
  cntA += __shfl_xor(cntA, 16);
  cntA += __shfl_xor(cntA, 32);
  cntB += __shfl_xor(cntB, 16);
  cntB += __shfl_xor(cntB, 32);
  const float invA = (cntA > 0) ? (1.0f / (float)cntA) : 0.0f;
  const float invB = (cntB > 0) ? (1.0f / (float)cntB) : 0.0f;

  // ---- epilogue: C/D layout col = lane&15, row = kq*4 + reg ----
#pragma unroll
  for (int r = 0; r < 4; ++r) {
    const int row = kq * 4 + r;
    const float invAr = __shfl(invA, row);   // lane 'row' holds row 'row' count (rows 0-15)
    const float invBr = __shfl(invB, row);   // same lane also holds row 'row+16' count
    float* orowA = out + (size_t)(t0 + row) * D_DIM + ntb * 16 + m;
    float* orowB = out + (size_t)(t0 + 16 + row) * D_DIM + ntb * 16 + m;
    orowA[0]  = a00[r] * invAr;
    orowA[16] = a01[r] * invAr;
    orowB[0]  = a10[r] * invBr;
    orowB[16] = a11[r] * invBr;
  }
}

extern "C" void kernel_launch(void* const* d_in, const int* in_sizes, int n_in,
                              void* d_out, int out_size, void* d_ws, size_t ws_size,
                              hipStream_t stream) {
  const float* flags = (const float*)d_in[0];
  const float* W     = (const float*)d_in[1];
  float* out         = (float*)d_out;

  hipLaunchKernelGGL(flagbag_kernel, dim3(512), dim3(1024), 0, stream, flags, W, out);
}

// Round 14
// 42.418 us; speedup vs baseline: 1.1280x; 1.1280x over previous
//
#include <hip/hip_runtime.h>
#include <stdint.h>

// FlagBagEncoder: out[t,:] = mean over {k : flags[t,k] > 0.5} of W[k,:], zeros if empty.
// T=100000, K=512, D=64, fp32 in/out.
//
// v14: v8 (best, 42.95 us) with SWAPPED MFMA OPERANDS in phase M.
//   D' = W_frag * mask_frag (A<->B swap; fragments are byte-identical, and v8's
//   correctness with the same k-map on both operands proves the HW A/B k-slot
//   maps match, so the sum is bit-identical). Verified C/D layout (col=lane&15
//   = B-col dim) now gives: lane holds OUTPUT ROW t = lane&15, n = 16nt+4kq+reg
//   -> 4 consecutive floats per acc -> epilogue is 4 coalesced dwordx4 stores
//   with NO cross-lane shuffles (lane already owns row t's count after the
//   shfl_xor reduce). v8 epilogue was 16 scalar stores + 4 shuffles in the
//   un-hideable post-stream tail.
// Everything else byte-identical to v8: stream-first row-sequential phase L,
// in-kernel W->sB convert overlapping streams, ONE barrier, 1024-thr blocks
// (80 KB LDS -> 2 blocks/CU = 32 waves/CU), grid 512, tile = wave*512 + bid.
// k-map (identical for A and B, permutation cancels): k = 128*kq + 8*s + e.

#define T_ROWS 100000
#define K_FLAGS 512
#define D_DIM 64
#define TILES (T_ROWS / 16)   // 6250, exact

typedef __attribute__((ext_vector_type(4))) float f32x4;
typedef __attribute__((ext_vector_type(8))) short bf16x8;

__device__ __forceinline__ uint32_t f32_to_bf16_rne(float f) {
  union { float f; uint32_t u; } v; v.f = f;
  uint32_t u = v.u;
  return (u + 0x7FFFu + ((u >> 16) & 1u)) >> 16;
}

__global__ __launch_bounds__(1024, 8) void flagbag_kernel(const float* __restrict__ flags,
                                                          const float* __restrict__ W,
                                                          float* __restrict__ out) {
  __shared__ uint4 sB[16 * 4 * 64];     // 64 KB W fragment table: E = s*256 + nt*64 + lane
  __shared__ uint32_t sM[16][256];      // 1 KB per wave mask exchange

  const int tid  = threadIdx.x;
  const int lane = tid & 63;
  const int wave = tid >> 6;
  const int tile = wave * 512 + (int)blockIdx.x;   // grid = 512 blocks exactly
  const bool active = (tile < TILES);
  const int t0 = (active ? tile : 0) * 16;

  // ---- phase L FIRST: row-sequential contiguous read of the 32-KB tile ----
  if (active) {
    const float* ft = flags + (size_t)t0 * K_FLAGS + lane * 8;

    uint32_t D0 = 0, D1 = 0, D2 = 0, D3 = 0;   // rows 0-3 / 4-7 / 8-11 / 12-15
    f32x4 ra[4], rb[4];
#pragma unroll
    for (int r = 0; r < 3; ++r) {
      ra[r] = *reinterpret_cast<const f32x4*>(ft + r * K_FLAGS);
      rb[r] = *reinterpret_cast<const f32x4*>(ft + r * K_FLAGS + 4);
    }
#pragma unroll
    for (int r = 0; r < 16; ++r) {
      if (r + 3 < 16) {   // compile-time under full unroll
        ra[(r + 3) & 3] = *reinterpret_cast<const f32x4*>(ft + (r + 3) * K_FLAGS);
        rb[(r + 3) & 3] = *reinterpret_cast<const f32x4*>(ft + (r + 3) * K_FLAGS + 4);
      }
      const f32x4 a = ra[r & 3], b = rb[r & 3];
      uint32_t byte = 0;
#pragma unroll
      for (int j = 0; j < 4; ++j) {
        byte |= (a[j] > 0.5f) ? (1u << j)       : 0u;
        byte |= (b[j] > 0.5f) ? (1u << (j + 4)) : 0u;
      }
      const uint32_t sh = byte << ((r & 3) * 8);
      if ((r >> 2) == 0) D0 |= sh;
      else if ((r >> 2) == 1) D1 |= sh;
      else if ((r >> 2) == 2) D2 |= sh;
      else D3 |= sh;
    }

    uint32_t* sMw = sM[wave];
    sMw[0 * 64 + (lane ^ 0)]  = D0;
    sMw[1 * 64 + (lane ^ 4)]  = D1;
    sMw[2 * 64 + (lane ^ 8)]  = D2;
    sMw[3 * 64 + (lane ^ 12)] = D3;
  }

  // ---- W -> bf16 fragment table (overlaps other waves' streams) ----
#pragma unroll
  for (int p = 0; p < 4; ++p) {
    const int E  = tid + p * 1024;
    const int s  = E >> 8;
    const int nt = (E >> 6) & 3;
    const int ln = E & 63;
    const int n  = (ln & 15) + 16 * nt;
    const int kb = 128 * (ln >> 4) + 8 * s;
    uint32_t r[4];
#pragma unroll
    for (int j = 0; j < 4; ++j) {
      uint32_t lo = f32_to_bf16_rne(W[(size_t)(kb + 2 * j    ) * D_DIM + n]);
      uint32_t hi = f32_to_bf16_rne(W[(size_t)(kb + 2 * j + 1) * D_DIM + n]);
      r[j] = lo | (hi << 16);
    }
    sB[E] = make_uint4(r[0], r[1], r[2], r[3]);
  }
  __syncthreads();   // only barrier: orders sB and sM
  if (!active) return;

  // ---- phase M: MFMA with SWAPPED operands (A = W frag, B = mask frag) ----
  const int m  = lane & 15;   // mask row (= output row this lane will OWN)
  const int kq = lane >> 4;
  const int mj = m >> 2, mb = m & 3;
  const int m4 = 4 * mj;
  const uint8_t* sMb = reinterpret_cast<const uint8_t*>(sM[wave]);
  const int C = 4 * (mj * 64 + 16 * kq) + mb;

  const uint4* sbl = &sB[lane];
  f32x4 acc[4];
#pragma unroll
  for (int nt = 0; nt < 4; ++nt) acc[nt] = (f32x4){0.f, 0.f, 0.f, 0.f};

  uint4 bc[4], bn[4];
#pragma unroll
  for (int nt = 0; nt < 4; ++nt) bc[nt] = sbl[nt * 64];

  int cnt = 0;
#pragma unroll
  for (int s = 0; s < 16; ++s) {
    if (s + 1 < 16) {
#pragma unroll
      for (int nt = 0; nt < 4; ++nt) bn[nt] = sbl[((s + 1) * 4 + nt) * 64];
    }
    const uint32_t byte = sMb[C + 4 * (s ^ m4)];   // 8 k-bits of row m, k=128kq+8s+e
    cnt += __popc(byte);
    bf16x8 af;
#pragma unroll
    for (int e = 0; e < 8; ++e) af[e] = ((byte >> e) & 1u) ? (short)0x3F80 : (short)0;

    // SWAPPED: A = W fragment, B = mask fragment.
    // C/D: col(lane&15) = mask row t ; row(kq*4+reg) = W col index -> n = 16nt+4kq+reg.
#pragma unroll
    for (int nt = 0; nt < 4; ++nt)
      acc[nt] = __builtin_amdgcn_mfma_f32_16x16x32_bf16(
          *reinterpret_cast<const bf16x8*>(&bc[nt]), af, acc[nt], 0, 0, 0);

#pragma unroll
    for (int nt = 0; nt < 4; ++nt) bc[nt] = bn[nt];
  }

  // full row-m count: lanes {m, m+16, m+32, m+48} hold disjoint k-quarters
  cnt += __shfl_xor(cnt, 16);
  cnt += __shfl_xor(cnt, 32);
  const float inv = (cnt > 0) ? (1.0f / (float)cnt) : 0.0f;

  // ---- epilogue: lane owns output row m; 4 consecutive floats per acc ----
  float* obase = out + (size_t)(t0 + m) * D_DIM + 4 * kq;
#pragma unroll
  for (int nt = 0; nt < 4; ++nt) {
    f32x4 v;
#pragma unroll
    for (int r = 0; r < 4; ++r) v[r] = acc[nt][r] * inv;
    *reinterpret_cast<f32x4*>(obase + 16 * nt) = v;   // coalesced dwordx4
  }
}

extern "C" void kernel_launch(void* const* d_in, const int* in_sizes, int n_in,
                              void* d_out, int out_size, void* d_ws, size_t ws_size,
                              hipStream_t stream) {
  const float* flags = (const float*)d_in[0];
  const float* W     = (const float*)d_in[1];
  float* out         = (float*)d_out;

  hipLaunchKernelGGL(flagbag_kernel, dim3(512), dim3(1024), 0, stream, flags, W, out);
}

// Round 15
// 41.525 us; speedup vs baseline: 1.1523x; 1.0215x over previous
//
#include <hip/hip_runtime.h>
#include <stdint.h>

// FlagBagEncoder: out[t,:] = mean over {k : flags[t,k] > 0.5} of W[k,:], zeros if empty.
// T=100000, K=512, D=64, fp32 in/out.
//
// v15: v14 (best, 42.42 us) with the phase-M af-build VALU replaced by LDS reads:
//   - 128-B nibble LUT (16 entries x 8 B: 4 bits -> 4 packed bf16 {0,1.0}) carved
//     from sM[15] (waves 13-15 are never active: max active wave = 12 since
//     tile = wave*512 + bid < 6250). LDS total stays 80 KB -> 2 blocks/CU.
//   - af = 2x ds_read_b64 (lo/hi nibble) instead of ~24 VALU/step. Same-address
//     lanes broadcast; <=16 distinct 8-B addrs -> <=2-way banks (free).
//   - mask bytes: 4x ds_read_b128 (one per 4-step group; the XOR exchange layout
//     makes each group's dwords consecutive) + 2-op byte extract, replacing 16
//     ds_read_u8. Evidence tail is VALU-bound: v13 halved B-LDS reads but
//     doubled af-builds and regressed 5 us.
// Unchanged from v14: stream-first row-sequential phase L, in-kernel W->sB
// convert overlapping streams, ONE barrier, swapped-operand MFMA (lane owns
// output row -> coalesced dwordx4 epilogue), 1024-thr blocks (32 waves/CU),
// grid 512, tile = wave*512 + bid.
// k-map (identical for A and B, permutation cancels): k = 128*kq + 8*s + e.

#define T_ROWS 100000
#define K_FLAGS 512
#define D_DIM 64
#define TILES (T_ROWS / 16)   // 6250, exact

typedef __attribute__((ext_vector_type(4))) float f32x4;
typedef __attribute__((ext_vector_type(8))) short bf16x8;

__device__ __forceinline__ uint32_t f32_to_bf16_rne(float f) {
  union { float f; uint32_t u; } v; v.f = f;
  uint32_t u = v.u;
  return (u + 0x7FFFu + ((u >> 16) & 1u)) >> 16;
}

__global__ __launch_bounds__(1024, 8) void flagbag_kernel(const float* __restrict__ flags,
                                                          const float* __restrict__ W,
                                                          float* __restrict__ out) {
  __shared__ uint4 sB[16 * 4 * 64];     // 64 KB W fragment table: E = s*256 + nt*64 + lane
  __shared__ uint32_t sM[16][256];      // 1 KB per wave mask exchange; sM[15] hosts the LUT

  const int tid  = threadIdx.x;
  const int lane = tid & 63;
  const int wave = tid >> 6;
  const int tile = wave * 512 + (int)blockIdx.x;   // grid = 512 blocks exactly
  const bool active = (tile < TILES);              // waves 13..15: never active
  const int t0 = (active ? tile : 0) * 16;

  // ---- phase L FIRST: row-sequential contiguous read of the 32-KB tile ----
  if (active) {
    const float* ft = flags + (size_t)t0 * K_FLAGS + lane * 8;

    uint32_t D0 = 0, D1 = 0, D2 = 0, D3 = 0;   // rows 0-3 / 4-7 / 8-11 / 12-15
    f32x4 ra[4], rb[4];
#pragma unroll
    for (int r = 0; r < 3; ++r) {
      ra[r] = *reinterpret_cast<const f32x4*>(ft + r * K_FLAGS);
      rb[r] = *reinterpret_cast<const f32x4*>(ft + r * K_FLAGS + 4);
    }
#pragma unroll
    for (int r = 0; r < 16; ++r) {
      if (r + 3 < 16) {   // compile-time under full unroll
        ra[(r + 3) & 3] = *reinterpret_cast<const f32x4*>(ft + (r + 3) * K_FLAGS);
        rb[(r + 3) & 3] = *reinterpret_cast<const f32x4*>(ft + (r + 3) * K_FLAGS + 4);
      }
      const f32x4 a = ra[r & 3], b = rb[r & 3];
      uint32_t byte = 0;
#pragma unroll
      for (int j = 0; j < 4; ++j) {
        byte |= (a[j] > 0.5f) ? (1u << j)       : 0u;
        byte |= (b[j] > 0.5f) ? (1u << (j + 4)) : 0u;
      }
      const uint32_t sh = byte << ((r & 3) * 8);
      if ((r >> 2) == 0) D0 |= sh;
      else if ((r >> 2) == 1) D1 |= sh;
      else if ((r >> 2) == 2) D2 |= sh;
      else D3 |= sh;
    }

    uint32_t* sMw = sM[wave];
    sMw[0 * 64 + (lane ^ 0)]  = D0;
    sMw[1 * 64 + (lane ^ 4)]  = D1;
    sMw[2 * 64 + (lane ^ 8)]  = D2;
    sMw[3 * 64 + (lane ^ 12)] = D3;
  }

  // ---- nibble LUT init: 16 entries x 2 dwords in sM[15] (dead space) ----
  if (tid < 32) {
    const int e = tid >> 1, h = tid & 1;   // entry nibble, dword half (bits 2h, 2h+1)
    const uint32_t d = (((e >> (2 * h)) & 1)     ? 0x00003F80u : 0u) |
                       (((e >> (2 * h + 1)) & 1) ? 0x3F800000u : 0u);
    sM[15][e * 2 + h] = d;
  }

  // ---- W -> bf16 fragment table (overlaps other waves' streams) ----
#pragma unroll
  for (int p = 0; p < 4; ++p) {
    const int E  = tid + p * 1024;
    const int s  = E >> 8;
    const int nt = (E >> 6) & 3;
    const int ln = E & 63;
    const int n  = (ln & 15) + 16 * nt;
    const int kb = 128 * (ln >> 4) + 8 * s;
    uint32_t r[4];
#pragma unroll
    for (int j = 0; j < 4; ++j) {
      uint32_t lo = f32_to_bf16_rne(W[(size_t)(kb + 2 * j    ) * D_DIM + n]);
      uint32_t hi = f32_to_bf16_rne(W[(size_t)(kb + 2 * j + 1) * D_DIM + n]);
      r[j] = lo | (hi << 16);
    }
    sB[E] = make_uint4(r[0], r[1], r[2], r[3]);
  }
  __syncthreads();   // only barrier: orders sB, sM, LUT
  if (!active) return;

  // ---- phase M: swapped-operand MFMA; af from LUT, mask dwords via b128 ----
  const int m  = lane & 15;   // mask row (= output row this lane OWNS)
  const int kq = lane >> 4;
  const int mj = m >> 2, mb = m & 3;
  const uint32_t* sMw = sM[wave];
  const uint32_t* lut = sM[15];

  const uint4* sbl = &sB[lane];
  f32x4 acc[4];
#pragma unroll
  for (int nt = 0; nt < 4; ++nt) acc[nt] = (f32x4){0.f, 0.f, 0.f, 0.f};

  uint4 bc[4], bn[4];
#pragma unroll
  for (int nt = 0; nt < 4; ++nt) bc[nt] = sbl[nt * 64];

  int cnt = 0;
#pragma unroll
  for (int g = 0; g < 4; ++g) {
    // steps 4g..4g+3: their mask dwords are consecutive (x = 16kq + s survives
    // the XOR remap since all offsets are 4-aligned): dword q <-> step 4g+q.
    const uint4 md = *reinterpret_cast<const uint4*>(&sMw[mj * 64 + 16 * kq + 4 * (g ^ mj)]);

#pragma unroll
    for (int q = 0; q < 4; ++q) {
      const int s = 4 * g + q;
      if (s + 1 < 16) {
#pragma unroll
        for (int nt = 0; nt < 4; ++nt) bn[nt] = sbl[((s + 1) * 4 + nt) * 64];
      }
      const uint32_t dw = (q == 0) ? md.x : (q == 1) ? md.y : (q == 2) ? md.z : md.w;
      const uint32_t byte = (dw >> (8 * mb)) & 0xFFu;   // 8 k-bits of row m, k=128kq+8s+e
      cnt += __popc(byte);

      // af via nibble LUT: dwords 0,1 <- lo nibble ; 2,3 <- hi nibble
      union { uint32_t d[4]; bf16x8 v; } af;
      const uint2 lo = *reinterpret_cast<const uint2*>(&lut[(byte & 15u) * 2]);
      const uint2 hi = *reinterpret_cast<const uint2*>(&lut[(byte >> 4) * 2]);
      af.d[0] = lo.x; af.d[1] = lo.y; af.d[2] = hi.x; af.d[3] = hi.y;

      // SWAPPED: A = W fragment, B = mask fragment.
#pragma unroll
      for (int nt = 0; nt < 4; ++nt)
        acc[nt] = __builtin_amdgcn_mfma_f32_16x16x32_bf16(
            *reinterpret_cast<const bf16x8*>(&bc[nt]), af.v, acc[nt], 0, 0, 0);

#pragma unroll
      for (int nt = 0; nt < 4; ++nt) bc[nt] = bn[nt];
    }
  }

  // full row-m count: lanes {m, m+16, m+32, m+48} hold disjoint k-quarters
  cnt += __shfl_xor(cnt, 16);
  cnt += __shfl_xor(cnt, 32);
  const float inv = (cnt > 0) ? (1.0f / (float)cnt) : 0.0f;

  // ---- epilogue: lane owns output row m; 4 coalesced dwordx4 stores ----
  float* obase = out + (size_t)(t0 + m) * D_DIM + 4 * kq;
#pragma unroll
  for (int nt = 0; nt < 4; ++nt) {
    f32x4 v;
#pragma unroll
    for (int r = 0; r < 4; ++r) v[r] = acc[nt][r] * inv;
    *reinterpret_cast<f32x4*>(obase + 16 * nt) = v;   // coalesced dwordx4
  }
}

extern "C" void kernel_launch(void* const* d_in, const int* in_sizes, int n_in,
                              void* d_out, int out_size, void* d_ws, size_t ws_size,
                              hipStream_t stream) {
  const float* flags = (const float*)d_in[0];
  const float* W     = (const float*)d_in[1];
  float* out         = (float*)d_out;

  hipLaunchKernelGGL(flagbag_kernel, dim3(512), dim3(1024), 0, stream, flags, W, out);
}